// Round 16
// baseline (102.697 us; speedup 1.0000x reference)
//
#include <hip/hip_runtime.h>
#include <hip/hip_bf16.h>
#include <cstdint>

#define NEGV -1e30f

constexpr int B = 16, T = 1024, D = 512, V = 5000, L = 64;
constexpr int NJ = 66;    // col 0 blank, col 1 class-1, cols 2..65 = labels
constexpr int NJP = 80;   // padded col count (5 MFMA n-tiles of 16)
#define LOG2E 1.4426950408889634f
#define LN2   0.6931471805599453f
#define PSH   6.0f   // probs pre-scaled by 2^6

typedef __attribute__((ext_vector_type(8))) short bf16x8;
typedef __attribute__((ext_vector_type(4))) int   i32x4;
typedef __attribute__((ext_vector_type(4))) float f32x4;

template <int CTRL>
__device__ __forceinline__ float dppf(float x) {
    return __int_as_float(__builtin_amdgcn_update_dpp(
        __float_as_int(x), __float_as_int(x), CTRL, 0xf, 0xf, false));
}
// shfl_up 1 across 64 lanes (wave_shr:1); lane0 <- fill  [HW-proven R5-R15]
__device__ __forceinline__ float shup1(float x, float fill) {
    int r = __builtin_amdgcn_update_dpp(__float_as_int(fill), __float_as_int(x),
                                        0x138, 0xf, 0xf, false);
    return __int_as_float(r);
}
__device__ __forceinline__ float wmax64(float x) {
    x = fmaxf(x, dppf<0x111>(x));
    x = fmaxf(x, dppf<0x112>(x));
    x = fmaxf(x, dppf<0x114>(x));
    x = fmaxf(x, dppf<0x118>(x));
    x = fmaxf(x, dppf<0x142>(x));
    x = fmaxf(x, dppf<0x143>(x));
    return __int_as_float(__builtin_amdgcn_readlane(__float_as_int(x), 63));
}
// 3-level-chain linear CTC step. cpl = skm * p_l (precomputed off-chain).
__device__ __forceinline__ void ctc_step2(float& aA, float& aB, float& aE,
        float p_b, float p_l, float cpl) {
    float pA = shup1(aA, 0.f);
    float pB = shup1(aB, 0.f);
    float tS = aA + aB;
    float tA = aA * p_b;
    float tE = aE * p_b;
    float tP = pA * cpl;
    float nA = fmaf(pB, p_b, tA);
    float nB = fmaf(tS, p_l, tP);
    float nE = fmaf(aB, p_b, tE);
    aA = nA; aB = nB; aE = nE;
}
__device__ __forceinline__ void ctc_step2_g(float& aA, float& aB, float& aE,
        float p_b, float p_l, float cpl, bool upd) {
    float pA = shup1(aA, 0.f);
    float pB = shup1(aB, 0.f);
    float tS = aA + aB;
    float tA = aA * p_b;
    float tE = aE * p_b;
    float tP = pA * cpl;
    float nA = fmaf(pB, p_b, tA);
    float nB = fmaf(tS, p_l, tP);
    float nE = fmaf(aB, p_b, tE);
    if (upd) { aA = nA; aB = nB; aE = nE; }
}
__device__ __forceinline__ void renorm(float& x0, float& x1, float& x2, int& Esum) {
    float m = wmax64(fmaxf(fmaxf(x0, x1), x2));
    int e = ((__float_as_int(m) >> 23) & 255) - 127;
    float sc = __int_as_float((127 - e) << 23);   // exact 2^-e
    x0 *= sc; x1 *= sc; x2 *= sc; Esum += e;
}
__device__ __forceinline__ int pk2(float lo, float hi) {   // 2xf32 -> 2xbf16 (trunc)
    return (int)((__float_as_uint(hi) & 0xFFFF0000u) | (__float_as_uint(lo) >> 16));
}

// ---------------- K1: gather W cols -> bf16 WgtT[b][80][512]; zero d_out -----
__global__ __launch_bounds__(256) void k_gather(const float* __restrict__ W,
        const float* __restrict__ bias, const int* __restrict__ ys,
        short* __restrict__ WgtT, float* __restrict__ biasG,
        unsigned* __restrict__ foMask, float* __restrict__ out) {
    int b = blockIdx.x, c = blockIdx.y, tid = threadIdx.x;
    if (b == 0 && c == 0 && tid == 0) out[0] = 0.f;   // k_ctc accumulates into it
    __shared__ int cls[NJP];
    __shared__ unsigned mw[3];
    if (tid < NJP) cls[tid] = (tid < 2) ? tid : (tid < NJ ? ys[b * L + tid - 2] : 0);
    if (tid < 3) mw[tid] = 0u;
    __syncthreads();
    if (c == 0) {
        if (tid < NJ) {
            bool first = true;
            for (int k = 0; k < tid; ++k) if (cls[k] == cls[tid]) { first = false; break; }
            if (first) atomicOr(&mw[tid >> 5], 1u << (tid & 31));
        }
        __syncthreads();
        if (tid < 3) foMask[b * 4 + tid] = mw[tid];
        if (tid == 3) foMask[b * 4 + 3] = 0u;
        if (tid < NJP) biasG[b * NJP + tid] = (tid < NJ) ? bias[cls[tid]] : 0.f;
    }
    int kt = tid & 63, jg = tid >> 6;
    for (int j = jg; j < NJP; j += 4) {
        int d = c * 64 + kt;
        float v = (j < NJ) ? W[(size_t)d * V + cls[j]] : 0.f;
        WgtT[((size_t)b * NJP + j) * D + d] = (short)(__float_as_uint(v) >> 16);
    }
}

// ---------------- K2: MFMA masked GEMM + deduped LSE -> scaled linear probs --
// grid (T/32, B), block 64 (1 wave). 32 t-rows x 80 cols: 2 A-fragments share
// each B-fragment load (B-stream issue halved vs 16-row tile).
__global__ __launch_bounds__(64) void k_scores(const float* __restrict__ hs,
        const short* __restrict__ WgtT, const float* __restrict__ biasG,
        const unsigned* __restrict__ foMask,
        float* __restrict__ lpb, float* __restrict__ lplT) {
    int b = blockIdx.y, t0 = blockIdx.x * 32;
    int lane = threadIdx.x, cl = lane & 15, kg = lane >> 4;

    f32x4 acc0[5], acc1[5];
    const float* __restrict__ bg = biasG + b * NJP;
    #pragma unroll
    for (int nt = 0; nt < 5; ++nt) {
        float bv = bg[nt * 16 + cl];
        acc0[nt] = (f32x4){bv, bv, bv, bv};
        acc1[nt] = (f32x4){bv, bv, bv, bv};
    }

    const float* __restrict__ arow0 = hs + ((size_t)(b * T) + t0 + cl) * D + kg * 8;
    const float* __restrict__ arow1 = arow0 + (size_t)16 * D;
    const short* __restrict__ brow = WgtT + ((size_t)b * NJP + cl) * D + kg * 8;

    #pragma unroll 4
    for (int ks = 0; ks < 16; ++ks) {
        int k0 = ks * 32;
        float4 a0 = *(const float4*)(arow0 + k0);
        float4 a1 = *(const float4*)(arow0 + k0 + 4);
        float4 a2 = *(const float4*)(arow1 + k0);
        float4 a3 = *(const float4*)(arow1 + k0 + 4);
        i32x4 ap0 = { pk2(a0.x, a0.y), pk2(a0.z, a0.w),
                      pk2(a1.x, a1.y), pk2(a1.z, a1.w) };
        i32x4 ap1 = { pk2(a2.x, a2.y), pk2(a2.z, a2.w),
                      pk2(a3.x, a3.y), pk2(a3.z, a3.w) };
        bf16x8 af0 = __builtin_bit_cast(bf16x8, ap0);
        bf16x8 af1 = __builtin_bit_cast(bf16x8, ap1);
        #pragma unroll
        for (int nt = 0; nt < 5; ++nt) {
            bf16x8 bf = *(const bf16x8*)(brow + (size_t)nt * 16 * D + k0);
            acc0[nt] = __builtin_amdgcn_mfma_f32_16x16x32_bf16(af0, bf, acc0[nt], 0, 0, 0);
            acc1[nt] = __builtin_amdgcn_mfma_f32_16x16x32_bf16(af1, bf, acc1[nt], 0, 0, 0);
        }
    }

    unsigned m0 = foMask[b * 4 + 0], m1 = foMask[b * 4 + 1], m2 = foMask[b * 4 + 2];
    bool on[5];
    on[0] = (m0 >> cl) & 1;        on[1] = (m0 >> (16 + cl)) & 1;
    on[2] = (m1 >> cl) & 1;        on[3] = (m1 >> (16 + cl)) & 1;
    on[4] = (cl < 2) ? ((m2 >> cl) & 1) : false;

    float lse0[4], lse1[4];
    #pragma unroll
    for (int r = 0; r < 4; ++r) {
        float mxa = NEGV, mxb = NEGV;
        #pragma unroll
        for (int nt = 0; nt < 5; ++nt) if (on[nt]) {
            mxa = fmaxf(mxa, acc0[nt][r]);
            mxb = fmaxf(mxb, acc1[nt][r]);
        }
        mxa = fmaxf(mxa, __shfl_xor(mxa, 1)); mxb = fmaxf(mxb, __shfl_xor(mxb, 1));
        mxa = fmaxf(mxa, __shfl_xor(mxa, 2)); mxb = fmaxf(mxb, __shfl_xor(mxb, 2));
        mxa = fmaxf(mxa, __shfl_xor(mxa, 4)); mxb = fmaxf(mxb, __shfl_xor(mxb, 4));
        mxa = fmaxf(mxa, __shfl_xor(mxa, 8)); mxb = fmaxf(mxb, __shfl_xor(mxb, 8));
        float sa = 0.f, sb = 0.f;
        #pragma unroll
        for (int nt = 0; nt < 5; ++nt) if (on[nt]) {
            sa += __expf(acc0[nt][r] - mxa);
            sb += __expf(acc1[nt][r] - mxb);
        }
        sa += __shfl_xor(sa, 1); sb += __shfl_xor(sb, 1);
        sa += __shfl_xor(sa, 2); sb += __shfl_xor(sb, 2);
        sa += __shfl_xor(sa, 4); sb += __shfl_xor(sb, 4);
        sa += __shfl_xor(sa, 8); sb += __shfl_xor(sb, 8);
        lse0[r] = mxa + __logf(sa);
        lse1[r] = mxb + __logf(sb);
    }

    __shared__ float Pt2[64][36];   // label x 32 t_local (144B rows, 16B-aligned)
    __shared__ float Pb[32];
    #pragma unroll
    for (int nt = 0; nt < 5; ++nt) {
        int col = nt * 16 + cl;
        #pragma unroll
        for (int r = 0; r < 4; ++r) {
            int t = kg * 4 + r;
            float pv0 = exp2f((acc0[nt][r] - lse0[r]) * LOG2E + PSH);
            float pv1 = exp2f((acc1[nt][r] - lse1[r]) * LOG2E + PSH);
            if (col == 0) { Pb[t] = pv0; Pb[t + 16] = pv1; }
            else if (col >= 2 && col < NJ) {
                Pt2[col - 2][t] = pv0;
                Pt2[col - 2][t + 16] = pv1;
            }
        }
    }
    __syncthreads();
    float* __restrict__ orow = lplT + (size_t)b * 64 * T + (size_t)lane * T + t0;
    #pragma unroll
    for (int i = 0; i < 8; ++i)
        *(float4*)(orow + 4 * i) = *(const float4*)&Pt2[lane][4 * i];
    if (lane < 8) {
        float4 v = make_float4(Pb[4*lane], Pb[4*lane+1], Pb[4*lane+2], Pb[4*lane+3]);
        *(float4*)(lpb + b * T + t0 + 4 * lane) = v;
    }
}

// ---------------- K3: CTC forward, LINEAR domain, one wave per batch ---------
// Register-pipelined prob streams; 3-level-chain step; renorm every 32 steps.
// Accumulates -ll/B into out[0] (zeroed by k_gather) -- no k_final kernel.
__global__ __launch_bounds__(64) void k_ctc(const float* __restrict__ lpb,
        const float* __restrict__ lplT, const int* __restrict__ ys,
        const int* __restrict__ hlens, const int* __restrict__ yslens,
        float* __restrict__ out) {
    int b = blockIdx.x, l = threadIdx.x;
    int lab = ys[b * L + l];
    int labm1 = __shfl_up(lab, 1);
    float skm = ((l >= 1) && (lab != 0) && (lab != labm1)) ? 1.0f : 0.0f;
    int hlen = hlens[b];
    int s2 = 2 * yslens[b];
    const float* __restrict__ lpbb = lpb + b * T;
    const float* __restrict__ lpt  = lplT + (size_t)b * 64 * T + (size_t)l * T;

    float aA = (l == 0) ? lpbb[0] : 0.f;
    float aB = (l == 0) ? lpt[0]  : 0.f;
    float aE = 0.f;
    int Esum = 0;

    float prl[15], prb[15];
    #pragma unroll
    for (int u = 0; u < 15; ++u) { prl[u] = lpt[1 + u]; prb[u] = lpbb[1 + u]; }
    float4 curl[4], curb[4], midl[4], midb[4], farl[4], farb[4];
    #pragma unroll
    for (int i = 0; i < 4; ++i) {
        curl[i] = *(const float4*)(lpt  + 16 + 4 * i);
        curb[i] = *(const float4*)(lpbb + 16 + 4 * i);
        midl[i] = *(const float4*)(lpt  + 32 + 4 * i);
        midb[i] = *(const float4*)(lpbb + 32 + 4 * i);
    }

    #pragma unroll
    for (int u = 0; u < 15; ++u) {
        int t = 1 + u;
        ctc_step2_g(aA, aB, aE, prb[u], prl[u], skm * prl[u], t < hlen);
    }
    renorm(aA, aB, aE, Esum);

    for (int g = 1; g < 64; ++g) {
        int t0 = 16 * g;
        if (g < 62) {
            const float* sl = lpt  + t0 + 32;
            const float* sb = lpbb + t0 + 32;
            #pragma unroll
            for (int i = 0; i < 4; ++i) {
                farl[i] = *(const float4*)(sl + 4 * i);
                farb[i] = *(const float4*)(sb + 4 * i);
            }
        }
        float pl[16], pb[16], cp[16];
        #pragma unroll
        for (int i = 0; i < 4; ++i) {
            pl[4*i+0] = curl[i].x; pl[4*i+1] = curl[i].y;
            pl[4*i+2] = curl[i].z; pl[4*i+3] = curl[i].w;
            pb[4*i+0] = curb[i].x; pb[4*i+1] = curb[i].y;
            pb[4*i+2] = curb[i].z; pb[4*i+3] = curb[i].w;
        }
        #pragma unroll
        for (int u = 0; u < 16; ++u) cp[u] = skm * pl[u];   // off-chain
        if (t0 + 16 <= hlen) {
            #pragma unroll
            for (int u = 0; u < 16; ++u)
                ctc_step2(aA, aB, aE, pb[u], pl[u], cp[u]);
        } else {
            #pragma unroll
            for (int u = 0; u < 16; ++u) {
                int t = t0 + u;
                ctc_step2_g(aA, aB, aE, pb[u], pl[u], cp[u], t < hlen);
            }
        }
        if ((g & 1) == 0 || g == 63) renorm(aA, aB, aE, Esum);  // every 32 steps
        #pragma unroll
        for (int i = 0; i < 4; ++i) {
            curl[i] = midl[i]; midl[i] = farl[i];
            curb[i] = midb[i]; midb[i] = farb[i];
        }
    }

    int s1 = s2 - 1;
    float v1 = __shfl(aB, s1 >> 1);
    float v2 = (s2 >= 2 * L) ? __shfl(aE, 63) : __shfl(aA, s2 >> 1);
    if (l == 0) {
        float llb = LN2 * (__log2f(v1 + v2) + (float)Esum - PSH * (float)hlen);
        atomicAdd(out, -llb * (1.0f / (float)B));
    }
}

extern "C" void kernel_launch(void* const* d_in, const int* in_sizes, int n_in,
                              void* d_out, int out_size, void* d_ws, size_t ws_size,
                              hipStream_t stream) {
    const float* hs    = (const float*)d_in[0];
    const float* W     = (const float*)d_in[1];
    const float* bias  = (const float*)d_in[2];
    const int*  hlens  = (const int*)d_in[3];
    const int*  ys     = (const int*)d_in[4];
    const int*  yslens = (const int*)d_in[5];

    char* ws = (char*)d_ws;
    unsigned* foMask = (unsigned*)(ws);            // 256 B
    float* biasG = (float*)(ws + 256);             // 16*80*4   -> 5376
    short* WgtT  = (short*)(ws + 5376);            // 16*80*512*2 -> 1316096
    float* lpb   = (float*)(ws + 1316096);         // 64 KB     -> 1381632
    float* lplT  = (float*)(ws + 1381632);         // [b][l][t] -> 5575936

    hipLaunchKernelGGL(k_gather, dim3(B, 8), dim3(256), 0, stream,
                       W, bias, ys, WgtT, biasG, foMask, (float*)d_out);
    hipLaunchKernelGGL(k_scores, dim3(T / 32, B), dim3(64), 0, stream,
                       hs, WgtT, biasG, foMask, lpb, lplT);
    hipLaunchKernelGGL(k_ctc, dim3(B), dim3(64), 0, stream,
                       lpb, lplT, ys, hlens, yslens, (float*)d_out);
}

// Round 17
// 87.954 us; speedup vs baseline: 1.1676x; 1.1676x over previous
//
#include <hip/hip_runtime.h>
#include <hip/hip_bf16.h>
#include <cstdint>

#define NEGV -1e30f

constexpr int B = 16, T = 1024, D = 512, V = 5000, L = 64;
constexpr int NJ = 66;    // col 0 blank, col 1 class-1, cols 2..65 = labels
constexpr int NJP = 80;   // padded col count (5 MFMA n-tiles of 16)
#define LOG2E 1.4426950408889634f
#define LN2   0.6931471805599453f
#define PSH   6.0f   // probs pre-scaled by 2^6

typedef __attribute__((ext_vector_type(8))) short bf16x8;
typedef __attribute__((ext_vector_type(4))) int   i32x4;
typedef __attribute__((ext_vector_type(4))) float f32x4;

template <int CTRL>
__device__ __forceinline__ float dppf(float x) {
    return __int_as_float(__builtin_amdgcn_update_dpp(
        __float_as_int(x), __float_as_int(x), CTRL, 0xf, 0xf, false));
}
// shfl_up 1 across 64 lanes (wave_shr:1); lane0 <- fill  [HW-proven R5-R15]
__device__ __forceinline__ float shup1(float x, float fill) {
    int r = __builtin_amdgcn_update_dpp(__float_as_int(fill), __float_as_int(x),
                                        0x138, 0xf, 0xf, false);
    return __int_as_float(r);
}
__device__ __forceinline__ float wmax64(float x) {
    x = fmaxf(x, dppf<0x111>(x));
    x = fmaxf(x, dppf<0x112>(x));
    x = fmaxf(x, dppf<0x114>(x));
    x = fmaxf(x, dppf<0x118>(x));
    x = fmaxf(x, dppf<0x142>(x));
    x = fmaxf(x, dppf<0x143>(x));
    return __int_as_float(__builtin_amdgcn_readlane(__float_as_int(x), 63));
}
// 3-level-chain linear CTC step. cpl = skm * p_l (precomputed off-chain).
__device__ __forceinline__ void ctc_step2(float& aA, float& aB, float& aE,
        float p_b, float p_l, float cpl) {
    float pA = shup1(aA, 0.f);
    float pB = shup1(aB, 0.f);
    float tS = aA + aB;
    float tA = aA * p_b;
    float tE = aE * p_b;
    float tP = pA * cpl;
    float nA = fmaf(pB, p_b, tA);
    float nB = fmaf(tS, p_l, tP);
    float nE = fmaf(aB, p_b, tE);
    aA = nA; aB = nB; aE = nE;
}
__device__ __forceinline__ void ctc_step2_g(float& aA, float& aB, float& aE,
        float p_b, float p_l, float cpl, bool upd) {
    float pA = shup1(aA, 0.f);
    float pB = shup1(aB, 0.f);
    float tS = aA + aB;
    float tA = aA * p_b;
    float tE = aE * p_b;
    float tP = pA * cpl;
    float nA = fmaf(pB, p_b, tA);
    float nB = fmaf(tS, p_l, tP);
    float nE = fmaf(aB, p_b, tE);
    if (upd) { aA = nA; aB = nB; aE = nE; }
}
__device__ __forceinline__ void renorm(float& x0, float& x1, float& x2, int& Esum) {
    float m = wmax64(fmaxf(fmaxf(x0, x1), x2));
    int e = ((__float_as_int(m) >> 23) & 255) - 127;
    float sc = __int_as_float((127 - e) << 23);   // exact 2^-e
    x0 *= sc; x1 *= sc; x2 *= sc; Esum += e;
}
__device__ __forceinline__ int pk2(float lo, float hi) {   // 2xf32 -> 2xbf16 (trunc)
    return (int)((__float_as_uint(hi) & 0xFFFF0000u) | (__float_as_uint(lo) >> 16));
}

// ---------------- K1: gather W cols -> bf16 WgtT[b][80][512]; zero d_out -----
__global__ __launch_bounds__(256) void k_gather(const float* __restrict__ W,
        const float* __restrict__ bias, const int* __restrict__ ys,
        short* __restrict__ WgtT, float* __restrict__ biasG,
        unsigned* __restrict__ foMask, float* __restrict__ out) {
    int b = blockIdx.x, c = blockIdx.y, tid = threadIdx.x;
    if (b == 0 && c == 0 && tid == 0) out[0] = 0.f;   // k_ctc accumulates into it
    __shared__ int cls[NJP];
    __shared__ unsigned mw[3];
    if (tid < NJP) cls[tid] = (tid < 2) ? tid : (tid < NJ ? ys[b * L + tid - 2] : 0);
    if (tid < 3) mw[tid] = 0u;
    __syncthreads();
    if (c == 0) {
        if (tid < NJ) {
            bool first = true;
            for (int k = 0; k < tid; ++k) if (cls[k] == cls[tid]) { first = false; break; }
            if (first) atomicOr(&mw[tid >> 5], 1u << (tid & 31));
        }
        __syncthreads();
        if (tid < 3) foMask[b * 4 + tid] = mw[tid];
        if (tid == 3) foMask[b * 4 + 3] = 0u;
        if (tid < NJP) biasG[b * NJP + tid] = (tid < NJ) ? bias[cls[tid]] : 0.f;
    }
    int kt = tid & 63, jg = tid >> 6;
    for (int j = jg; j < NJP; j += 4) {
        int d = c * 64 + kt;
        float v = (j < NJ) ? W[(size_t)d * V + cls[j]] : 0.f;
        WgtT[((size_t)b * NJP + j) * D + d] = (short)(__float_as_uint(v) >> 16);
    }
}

// ---------------- K2: MFMA masked GEMM + deduped LSE -> scaled linear probs --
// grid (T/16, B), block 64 (1 wave) -- R15-proven 16-row tile (max grid
// parallelism; 32-row tile regressed at 1 wave/SIMD occupancy, R16).
__global__ __launch_bounds__(64) void k_scores(const float* __restrict__ hs,
        const short* __restrict__ WgtT, const float* __restrict__ biasG,
        const unsigned* __restrict__ foMask,
        float* __restrict__ lpb, float* __restrict__ lplT) {
    int b = blockIdx.y, t0 = blockIdx.x * 16;
    int lane = threadIdx.x, cl = lane & 15, kg = lane >> 4;

    f32x4 acc[5];
    const float* __restrict__ bg = biasG + b * NJP;
    #pragma unroll
    for (int nt = 0; nt < 5; ++nt) {
        float bv = bg[nt * 16 + cl];
        acc[nt] = (f32x4){bv, bv, bv, bv};
    }

    const float* __restrict__ arow = hs + ((size_t)(b * T) + t0 + cl) * D + kg * 8;
    const short* __restrict__ brow = WgtT + ((size_t)b * NJP + cl) * D + kg * 8;

    #pragma unroll 4
    for (int ks = 0; ks < 16; ++ks) {
        int k0 = ks * 32;
        float4 a0 = *(const float4*)(arow + k0);
        float4 a1 = *(const float4*)(arow + k0 + 4);
        i32x4 ap = { pk2(a0.x, a0.y), pk2(a0.z, a0.w),
                     pk2(a1.x, a1.y), pk2(a1.z, a1.w) };
        bf16x8 af = __builtin_bit_cast(bf16x8, ap);
        #pragma unroll
        for (int nt = 0; nt < 5; ++nt) {
            bf16x8 bf = *(const bf16x8*)(brow + (size_t)nt * 16 * D + k0);
            acc[nt] = __builtin_amdgcn_mfma_f32_16x16x32_bf16(af, bf, acc[nt], 0, 0, 0);
        }
    }

    unsigned m0 = foMask[b * 4 + 0], m1 = foMask[b * 4 + 1], m2 = foMask[b * 4 + 2];
    bool on[5];
    on[0] = (m0 >> cl) & 1;        on[1] = (m0 >> (16 + cl)) & 1;
    on[2] = (m1 >> cl) & 1;        on[3] = (m1 >> (16 + cl)) & 1;
    on[4] = (cl < 2) ? ((m2 >> cl) & 1) : false;

    float lse[4];
    #pragma unroll
    for (int r = 0; r < 4; ++r) {
        float mx = NEGV;
        #pragma unroll
        for (int nt = 0; nt < 5; ++nt) if (on[nt]) mx = fmaxf(mx, acc[nt][r]);
        mx = fmaxf(mx, __shfl_xor(mx, 1));
        mx = fmaxf(mx, __shfl_xor(mx, 2));
        mx = fmaxf(mx, __shfl_xor(mx, 4));
        mx = fmaxf(mx, __shfl_xor(mx, 8));
        float s = 0.f;
        #pragma unroll
        for (int nt = 0; nt < 5; ++nt) if (on[nt]) s += __expf(acc[nt][r] - mx);
        s += __shfl_xor(s, 1);
        s += __shfl_xor(s, 2);
        s += __shfl_xor(s, 4);
        s += __shfl_xor(s, 8);
        lse[r] = mx + __logf(s);
    }

    __shared__ float Pt2[64][20];
    __shared__ float Pb[16];
    #pragma unroll
    for (int nt = 0; nt < 5; ++nt) {
        int col = nt * 16 + cl;
        #pragma unroll
        for (int r = 0; r < 4; ++r) {
            int t = kg * 4 + r;
            float pv = exp2f((acc[nt][r] - lse[r]) * LOG2E + PSH);
            if (col == 0) Pb[t] = pv;
            else if (col >= 2 && col < NJ) Pt2[col - 2][t] = pv;
        }
    }
    __syncthreads();
    float* __restrict__ orow = lplT + (size_t)b * 64 * T + (size_t)lane * T + t0;
    #pragma unroll
    for (int i = 0; i < 4; ++i)
        *(float4*)(orow + 4 * i) = *(const float4*)&Pt2[lane][4 * i];
    if (lane < 4) {
        float4 v = make_float4(Pb[4*lane], Pb[4*lane+1], Pb[4*lane+2], Pb[4*lane+3]);
        *(float4*)(lpb + b * T + t0 + 4 * lane) = v;
    }
}

// ---------------- K3: CTC forward, LINEAR domain, one wave per batch ---------
// Register-pipelined prob streams; 3-level-chain step; renorm every 32 steps.
// Accumulates -ll/B into out[0] (zeroed by k_gather) -- no k_final kernel.
__global__ __launch_bounds__(64) void k_ctc(const float* __restrict__ lpb,
        const float* __restrict__ lplT, const int* __restrict__ ys,
        const int* __restrict__ hlens, const int* __restrict__ yslens,
        float* __restrict__ out) {
    int b = blockIdx.x, l = threadIdx.x;
    int lab = ys[b * L + l];
    int labm1 = __shfl_up(lab, 1);
    float skm = ((l >= 1) && (lab != 0) && (lab != labm1)) ? 1.0f : 0.0f;
    int hlen = hlens[b];
    int s2 = 2 * yslens[b];
    const float* __restrict__ lpbb = lpb + b * T;
    const float* __restrict__ lpt  = lplT + (size_t)b * 64 * T + (size_t)l * T;

    float aA = (l == 0) ? lpbb[0] : 0.f;
    float aB = (l == 0) ? lpt[0]  : 0.f;
    float aE = 0.f;
    int Esum = 0;

    float prl[15], prb[15];
    #pragma unroll
    for (int u = 0; u < 15; ++u) { prl[u] = lpt[1 + u]; prb[u] = lpbb[1 + u]; }
    float4 curl[4], curb[4], midl[4], midb[4], farl[4], farb[4];
    #pragma unroll
    for (int i = 0; i < 4; ++i) {
        curl[i] = *(const float4*)(lpt  + 16 + 4 * i);
        curb[i] = *(const float4*)(lpbb + 16 + 4 * i);
        midl[i] = *(const float4*)(lpt  + 32 + 4 * i);
        midb[i] = *(const float4*)(lpbb + 32 + 4 * i);
    }

    #pragma unroll
    for (int u = 0; u < 15; ++u) {
        int t = 1 + u;
        ctc_step2_g(aA, aB, aE, prb[u], prl[u], skm * prl[u], t < hlen);
    }
    renorm(aA, aB, aE, Esum);

    for (int g = 1; g < 64; ++g) {
        int t0 = 16 * g;
        if (g < 62) {
            const float* sl = lpt  + t0 + 32;
            const float* sb = lpbb + t0 + 32;
            #pragma unroll
            for (int i = 0; i < 4; ++i) {
                farl[i] = *(const float4*)(sl + 4 * i);
                farb[i] = *(const float4*)(sb + 4 * i);
            }
        }
        float pl[16], pb[16], cp[16];
        #pragma unroll
        for (int i = 0; i < 4; ++i) {
            pl[4*i+0] = curl[i].x; pl[4*i+1] = curl[i].y;
            pl[4*i+2] = curl[i].z; pl[4*i+3] = curl[i].w;
            pb[4*i+0] = curb[i].x; pb[4*i+1] = curb[i].y;
            pb[4*i+2] = curb[i].z; pb[4*i+3] = curb[i].w;
        }
        #pragma unroll
        for (int u = 0; u < 16; ++u) cp[u] = skm * pl[u];   // off-chain
        if (t0 + 16 <= hlen) {
            #pragma unroll
            for (int u = 0; u < 16; ++u)
                ctc_step2(aA, aB, aE, pb[u], pl[u], cp[u]);
        } else {
            #pragma unroll
            for (int u = 0; u < 16; ++u) {
                int t = t0 + u;
                ctc_step2_g(aA, aB, aE, pb[u], pl[u], cp[u], t < hlen);
            }
        }
        if ((g & 1) == 0 || g == 63) renorm(aA, aB, aE, Esum);  // every 32 steps
        #pragma unroll
        for (int i = 0; i < 4; ++i) {
            curl[i] = midl[i]; midl[i] = farl[i];
            curb[i] = midb[i]; midb[i] = farb[i];
        }
    }

    int s1 = s2 - 1;
    float v1 = __shfl(aB, s1 >> 1);
    float v2 = (s2 >= 2 * L) ? __shfl(aE, 63) : __shfl(aA, s2 >> 1);
    if (l == 0) {
        float llb = LN2 * (__log2f(v1 + v2) + (float)Esum - PSH * (float)hlen);
        atomicAdd(out, -llb * (1.0f / (float)B));
    }
}

extern "C" void kernel_launch(void* const* d_in, const int* in_sizes, int n_in,
                              void* d_out, int out_size, void* d_ws, size_t ws_size,
                              hipStream_t stream) {
    const float* hs    = (const float*)d_in[0];
    const float* W     = (const float*)d_in[1];
    const float* bias  = (const float*)d_in[2];
    const int*  hlens  = (const int*)d_in[3];
    const int*  ys     = (const int*)d_in[4];
    const int*  yslens = (const int*)d_in[5];

    char* ws = (char*)d_ws;
    unsigned* foMask = (unsigned*)(ws);            // 256 B
    float* biasG = (float*)(ws + 256);             // 16*80*4   -> 5376
    short* WgtT  = (short*)(ws + 5376);            // 16*80*512*2 -> 1316096
    float* lpb   = (float*)(ws + 1316096);         // 64 KB     -> 1381632
    float* lplT  = (float*)(ws + 1381632);         // [b][l][t] -> 5575936

    hipLaunchKernelGGL(k_gather, dim3(B, 8), dim3(256), 0, stream,
                       W, bias, ys, WgtT, biasG, foMask, (float*)d_out);
    hipLaunchKernelGGL(k_scores, dim3(T / 16, B), dim3(64), 0, stream,
                       hs, WgtT, biasG, foMask, lpb, lplT);
    hipLaunchKernelGGL(k_ctc, dim3(B), dim3(64), 0, stream,
                       lpb, lplT, ys, hlens, yslens, (float*)d_out);
}

// Round 18
// 86.117 us; speedup vs baseline: 1.1925x; 1.0213x over previous
//
#include <hip/hip_runtime.h>
#include <hip/hip_bf16.h>
#include <cstdint>

#define NEGV -1e30f

constexpr int B = 16, T = 1024, D = 512, V = 5000, L = 64;
constexpr int NJ = 66;    // col 0 blank, col 1 class-1, cols 2..65 = labels
constexpr int NJP = 80;   // padded col count (5 MFMA n-tiles of 16)
#define LOG2E 1.4426950408889634f
#define LN2   0.6931471805599453f
#define PSH   6.0f   // probs pre-scaled by 2^6

typedef __attribute__((ext_vector_type(8))) short bf16x8;
typedef __attribute__((ext_vector_type(4))) int   i32x4;
typedef __attribute__((ext_vector_type(4))) float f32x4;

template <int CTRL>
__device__ __forceinline__ float dppf(float x) {
    return __int_as_float(__builtin_amdgcn_update_dpp(
        __float_as_int(x), __float_as_int(x), CTRL, 0xf, 0xf, false));
}
// shfl_up 1 across 64 lanes (wave_shr:1); lane0 <- fill  [HW-proven R5-R17]
__device__ __forceinline__ float shup1(float x, float fill) {
    int r = __builtin_amdgcn_update_dpp(__float_as_int(fill), __float_as_int(x),
                                        0x138, 0xf, 0xf, false);
    return __int_as_float(r);
}
__device__ __forceinline__ float wmax64(float x) {
    x = fmaxf(x, dppf<0x111>(x));
    x = fmaxf(x, dppf<0x112>(x));
    x = fmaxf(x, dppf<0x114>(x));
    x = fmaxf(x, dppf<0x118>(x));
    x = fmaxf(x, dppf<0x142>(x));
    x = fmaxf(x, dppf<0x143>(x));
    return __int_as_float(__builtin_amdgcn_readlane(__float_as_int(x), 63));
}
// 3-level-chain linear CTC step. cpl = skm * p_l (precomputed off-chain).
__device__ __forceinline__ void ctc_step2(float& aA, float& aB, float& aE,
        float p_b, float p_l, float cpl) {
    float pA = shup1(aA, 0.f);
    float pB = shup1(aB, 0.f);
    float tS = aA + aB;
    float tA = aA * p_b;
    float tE = aE * p_b;
    float tP = pA * cpl;
    float nA = fmaf(pB, p_b, tA);
    float nB = fmaf(tS, p_l, tP);
    float nE = fmaf(aB, p_b, tE);
    aA = nA; aB = nB; aE = nE;
}
__device__ __forceinline__ void ctc_step2_g(float& aA, float& aB, float& aE,
        float p_b, float p_l, float cpl, bool upd) {
    float pA = shup1(aA, 0.f);
    float pB = shup1(aB, 0.f);
    float tS = aA + aB;
    float tA = aA * p_b;
    float tE = aE * p_b;
    float tP = pA * cpl;
    float nA = fmaf(pB, p_b, tA);
    float nB = fmaf(tS, p_l, tP);
    float nE = fmaf(aB, p_b, tE);
    if (upd) { aA = nA; aB = nB; aE = nE; }
}
__device__ __forceinline__ void renorm(float& x0, float& x1, float& x2, int& Esum) {
    float m = wmax64(fmaxf(fmaxf(x0, x1), x2));
    int e = ((__float_as_int(m) >> 23) & 255) - 127;
    float sc = __int_as_float((127 - e) << 23);   // exact 2^-e
    x0 *= sc; x1 *= sc; x2 *= sc; Esum += e;
}
__device__ __forceinline__ int pk2(float lo, float hi) {   // 2xf32 -> 2xbf16 (trunc)
    return (int)((__float_as_uint(hi) & 0xFFFF0000u) | (__float_as_uint(lo) >> 16));
}

// ---------------- K1: gather W cols -> bf16 WgtT[b][80][512]; zero d_out -----
__global__ __launch_bounds__(256) void k_gather(const float* __restrict__ W,
        const float* __restrict__ bias, const int* __restrict__ ys,
        short* __restrict__ WgtT, float* __restrict__ biasG,
        unsigned* __restrict__ foMask, float* __restrict__ out) {
    int b = blockIdx.x, c = blockIdx.y, tid = threadIdx.x;
    if (b == 0 && c == 0 && tid == 0) out[0] = 0.f;   // k_ctc accumulates into it
    __shared__ int cls[NJP];
    __shared__ unsigned mw[3];
    if (tid < NJP) cls[tid] = (tid < 2) ? tid : (tid < NJ ? ys[b * L + tid - 2] : 0);
    if (tid < 3) mw[tid] = 0u;
    __syncthreads();
    if (c == 0) {
        if (tid < NJ) {
            bool first = true;
            for (int k = 0; k < tid; ++k) if (cls[k] == cls[tid]) { first = false; break; }
            if (first) atomicOr(&mw[tid >> 5], 1u << (tid & 31));
        }
        __syncthreads();
        if (tid < 3) foMask[b * 4 + tid] = mw[tid];
        if (tid == 3) foMask[b * 4 + 3] = 0u;
        if (tid < NJP) biasG[b * NJP + tid] = (tid < NJ) ? bias[cls[tid]] : 0.f;
    }
    int kt = tid & 63, jg = tid >> 6;
    for (int j = jg; j < NJP; j += 4) {
        int d = c * 64 + kt;
        float v = (j < NJ) ? W[(size_t)d * V + cls[j]] : 0.f;
        WgtT[((size_t)b * NJP + j) * D + d] = (short)(__float_as_uint(v) >> 16);
    }
}

// ---------------- K2: MFMA masked GEMM + deduped LSE -> scaled linear probs --
// grid (T/16, B), block 64 (1 wave). 16-row tile (R17-proven). K-loop
// restructured for latency: ALL 32 A-loads hoisted into one burst (addresses
// known at entry -> 1 exposed HBM round-trip instead of 16); B-loads depth-2
// software-pipelined (L2-resident).
__global__ __launch_bounds__(64) void k_scores(const float* __restrict__ hs,
        const short* __restrict__ WgtT, const float* __restrict__ biasG,
        const unsigned* __restrict__ foMask,
        float* __restrict__ lpb, float* __restrict__ lplT) {
    int b = blockIdx.y, t0 = blockIdx.x * 16;
    int lane = threadIdx.x, cl = lane & 15, kg = lane >> 4;

    f32x4 acc[5];
    const float* __restrict__ bg = biasG + b * NJP;
    #pragma unroll
    for (int nt = 0; nt < 5; ++nt) {
        float bv = bg[nt * 16 + cl];
        acc[nt] = (f32x4){bv, bv, bv, bv};
    }

    const float* __restrict__ arow = hs + ((size_t)(b * T) + t0 + cl) * D + kg * 8;
    const short* __restrict__ brow = WgtT + ((size_t)b * NJP + cl) * D + kg * 8;

    // burst-load the whole A row-slice: 32 independent float4 loads
    float4 a[32];
    #pragma unroll
    for (int ks = 0; ks < 16; ++ks) {
        a[2 * ks]     = *(const float4*)(arow + 32 * ks);
        a[2 * ks + 1] = *(const float4*)(arow + 32 * ks + 4);
    }
    // B depth-2 pipeline
    bf16x8 bcur[5], bnx[5];
    #pragma unroll
    for (int nt = 0; nt < 5; ++nt)
        bcur[nt] = *(const bf16x8*)(brow + (size_t)nt * 16 * D);

    #pragma unroll
    for (int ks = 0; ks < 16; ++ks) {
        if (ks < 15) {
            #pragma unroll
            for (int nt = 0; nt < 5; ++nt)
                bnx[nt] = *(const bf16x8*)(brow + (size_t)nt * 16 * D + 32 * (ks + 1));
        }
        i32x4 ap = { pk2(a[2*ks].x, a[2*ks].y),   pk2(a[2*ks].z, a[2*ks].w),
                     pk2(a[2*ks+1].x, a[2*ks+1].y), pk2(a[2*ks+1].z, a[2*ks+1].w) };
        bf16x8 af = __builtin_bit_cast(bf16x8, ap);
        #pragma unroll
        for (int nt = 0; nt < 5; ++nt)
            acc[nt] = __builtin_amdgcn_mfma_f32_16x16x32_bf16(af, bcur[nt], acc[nt], 0, 0, 0);
        #pragma unroll
        for (int nt = 0; nt < 5; ++nt) bcur[nt] = bnx[nt];
    }

    unsigned m0 = foMask[b * 4 + 0], m1 = foMask[b * 4 + 1], m2 = foMask[b * 4 + 2];
    bool on[5];
    on[0] = (m0 >> cl) & 1;        on[1] = (m0 >> (16 + cl)) & 1;
    on[2] = (m1 >> cl) & 1;        on[3] = (m1 >> (16 + cl)) & 1;
    on[4] = (cl < 2) ? ((m2 >> cl) & 1) : false;

    float lse[4];
    #pragma unroll
    for (int r = 0; r < 4; ++r) {
        float mx = NEGV;
        #pragma unroll
        for (int nt = 0; nt < 5; ++nt) if (on[nt]) mx = fmaxf(mx, acc[nt][r]);
        mx = fmaxf(mx, __shfl_xor(mx, 1));
        mx = fmaxf(mx, __shfl_xor(mx, 2));
        mx = fmaxf(mx, __shfl_xor(mx, 4));
        mx = fmaxf(mx, __shfl_xor(mx, 8));
        float s = 0.f;
        #pragma unroll
        for (int nt = 0; nt < 5; ++nt) if (on[nt]) s += __expf(acc[nt][r] - mx);
        s += __shfl_xor(s, 1);
        s += __shfl_xor(s, 2);
        s += __shfl_xor(s, 4);
        s += __shfl_xor(s, 8);
        lse[r] = mx + __logf(s);
    }

    __shared__ float Pt2[64][20];
    __shared__ float Pb[16];
    #pragma unroll
    for (int nt = 0; nt < 5; ++nt) {
        int col = nt * 16 + cl;
        #pragma unroll
        for (int r = 0; r < 4; ++r) {
            int t = kg * 4 + r;
            float pv = exp2f((acc[nt][r] - lse[r]) * LOG2E + PSH);
            if (col == 0) Pb[t] = pv;
            else if (col >= 2 && col < NJ) Pt2[col - 2][t] = pv;
        }
    }
    __syncthreads();
    float* __restrict__ orow = lplT + (size_t)b * 64 * T + (size_t)lane * T + t0;
    #pragma unroll
    for (int i = 0; i < 4; ++i)
        *(float4*)(orow + 4 * i) = *(const float4*)&Pt2[lane][4 * i];
    if (lane < 4) {
        float4 v = make_float4(Pb[4*lane], Pb[4*lane+1], Pb[4*lane+2], Pb[4*lane+3]);
        *(float4*)(lpb + b * T + t0 + 4 * lane) = v;
    }
}

// ---------------- K3: CTC forward, LINEAR domain, one wave per batch ---------
// Register-pipelined prob streams; 3-level-chain step; renorm every 32 steps.
// Accumulates -ll/B into out[0] (zeroed by k_gather) -- no k_final kernel.
__global__ __launch_bounds__(64) void k_ctc(const float* __restrict__ lpb,
        const float* __restrict__ lplT, const int* __restrict__ ys,
        const int* __restrict__ hlens, const int* __restrict__ yslens,
        float* __restrict__ out) {
    int b = blockIdx.x, l = threadIdx.x;
    int lab = ys[b * L + l];
    int labm1 = __shfl_up(lab, 1);
    float skm = ((l >= 1) && (lab != 0) && (lab != labm1)) ? 1.0f : 0.0f;
    int hlen = hlens[b];
    int s2 = 2 * yslens[b];
    const float* __restrict__ lpbb = lpb + b * T;
    const float* __restrict__ lpt  = lplT + (size_t)b * 64 * T + (size_t)l * T;

    float aA = (l == 0) ? lpbb[0] : 0.f;
    float aB = (l == 0) ? lpt[0]  : 0.f;
    float aE = 0.f;
    int Esum = 0;

    float prl[15], prb[15];
    #pragma unroll
    for (int u = 0; u < 15; ++u) { prl[u] = lpt[1 + u]; prb[u] = lpbb[1 + u]; }
    float4 curl[4], curb[4], midl[4], midb[4], farl[4], farb[4];
    #pragma unroll
    for (int i = 0; i < 4; ++i) {
        curl[i] = *(const float4*)(lpt  + 16 + 4 * i);
        curb[i] = *(const float4*)(lpbb + 16 + 4 * i);
        midl[i] = *(const float4*)(lpt  + 32 + 4 * i);
        midb[i] = *(const float4*)(lpbb + 32 + 4 * i);
    }

    #pragma unroll
    for (int u = 0; u < 15; ++u) {
        int t = 1 + u;
        ctc_step2_g(aA, aB, aE, prb[u], prl[u], skm * prl[u], t < hlen);
    }
    renorm(aA, aB, aE, Esum);

    for (int g = 1; g < 64; ++g) {
        int t0 = 16 * g;
        if (g < 62) {
            const float* sl = lpt  + t0 + 32;
            const float* sb = lpbb + t0 + 32;
            #pragma unroll
            for (int i = 0; i < 4; ++i) {
                farl[i] = *(const float4*)(sl + 4 * i);
                farb[i] = *(const float4*)(sb + 4 * i);
            }
        }
        float pl[16], pb[16], cp[16];
        #pragma unroll
        for (int i = 0; i < 4; ++i) {
            pl[4*i+0] = curl[i].x; pl[4*i+1] = curl[i].y;
            pl[4*i+2] = curl[i].z; pl[4*i+3] = curl[i].w;
            pb[4*i+0] = curb[i].x; pb[4*i+1] = curb[i].y;
            pb[4*i+2] = curb[i].z; pb[4*i+3] = curb[i].w;
        }
        #pragma unroll
        for (int u = 0; u < 16; ++u) cp[u] = skm * pl[u];   // off-chain
        if (t0 + 16 <= hlen) {
            #pragma unroll
            for (int u = 0; u < 16; ++u)
                ctc_step2(aA, aB, aE, pb[u], pl[u], cp[u]);
        } else {
            #pragma unroll
            for (int u = 0; u < 16; ++u) {
                int t = t0 + u;
                ctc_step2_g(aA, aB, aE, pb[u], pl[u], cp[u], t < hlen);
            }
        }
        if ((g & 1) == 0 || g == 63) renorm(aA, aB, aE, Esum);  // every 32 steps
        #pragma unroll
        for (int i = 0; i < 4; ++i) {
            curl[i] = midl[i]; midl[i] = farl[i];
            curb[i] = midb[i]; midb[i] = farb[i];
        }
    }

    int s1 = s2 - 1;
    float v1 = __shfl(aB, s1 >> 1);
    float v2 = (s2 >= 2 * L) ? __shfl(aE, 63) : __shfl(aA, s2 >> 1);
    if (l == 0) {
        float llb = LN2 * (__log2f(v1 + v2) + (float)Esum - PSH * (float)hlen);
        atomicAdd(out, -llb * (1.0f / (float)B));
    }
}

extern "C" void kernel_launch(void* const* d_in, const int* in_sizes, int n_in,
                              void* d_out, int out_size, void* d_ws, size_t ws_size,
                              hipStream_t stream) {
    const float* hs    = (const float*)d_in[0];
    const float* W     = (const float*)d_in[1];
    const float* bias  = (const float*)d_in[2];
    const int*  hlens  = (const int*)d_in[3];
    const int*  ys     = (const int*)d_in[4];
    const int*  yslens = (const int*)d_in[5];

    char* ws = (char*)d_ws;
    unsigned* foMask = (unsigned*)(ws);            // 256 B
    float* biasG = (float*)(ws + 256);             // 16*80*4   -> 5376
    short* WgtT  = (short*)(ws + 5376);            // 16*80*512*2 -> 1316096
    float* lpb   = (float*)(ws + 1316096);         // 64 KB     -> 1381632
    float* lplT  = (float*)(ws + 1381632);         // [b][l][t] -> 5575936

    hipLaunchKernelGGL(k_gather, dim3(B, 8), dim3(256), 0, stream,
                       W, bias, ys, WgtT, biasG, foMask, (float*)d_out);
    hipLaunchKernelGGL(k_scores, dim3(T / 16, B), dim3(64), 0, stream,
                       hs, WgtT, biasG, foMask, lpb, lplT);
    hipLaunchKernelGGL(k_ctc, dim3(B), dim3(64), 0, stream,
                       lpb, lplT, ys, hlens, yslens, (float*)d_out);
}